// Round 10
// baseline (150.105 us; speedup 1.0000x reference)
//
#include <hip/hip_runtime.h>
#include <hip/hip_bf16.h>

#define D_IN   128
#define D_OUT  64
#define MAX_USHORT_NODES 65536
#define BIN_SHIFT 7          // 128 node ids per bin
#define BIN_NODES 128
#define MAX_BINS  512        // supports n_nodes <= 65536
#define BIN_CAP   4096       // scratch slots per bin (expected ~2046)
#define P1_EDGES  4096       // edges per pass-1 sorter block
#define GT_THREADS 512

using frag_ab = __attribute__((ext_vector_type(8))) short;  // 8 bf16
using frag_cd = __attribute__((ext_vector_type(4))) float;  // 4 fp32

static __device__ __forceinline__ short f2bf(float f) {
    union { float f; unsigned u; } v; v.f = f;
    unsigned r = v.u + 0x7FFFu + ((v.u >> 16) & 1u);   // RNE truncate to bf16
    return (short)(r >> 16);
}
static __device__ __forceinline__ float bf1(unsigned short s) {
    union { unsigned u; float f; } v; v.u = ((unsigned)s) << 16; return v.f;
}

// ---------------------------------------------------------------------------
// Fused prep: blocks [0, proj_blocks) = MFMA projection (wave = 16-node
// tile). Blocks [proj_blocks, ...) = bin pass 1 as a block-local LDS
// counting sort: histogram -> prefix scan -> LDS-sorted records -> claim
// contiguous bin ranges -> SEGMENT-CONTIGUOUS coalesced stores to scratch.
// Record format: r | c<<16.
// ---------------------------------------------------------------------------
__global__ void prep_kernel(const float* __restrict__ x,
                            const float* __restrict__ W,
                            const float* __restrict__ bvec,
                            unsigned short* __restrict__ h,
                            const int* __restrict__ row,
                            const int* __restrict__ col,
                            unsigned* __restrict__ scratch,
                            int* __restrict__ cursor,
                            int* __restrict__ ovfA_cnt,
                            unsigned* __restrict__ ovfA_list,
                            int ovfA_cap, int n_nodes, int n_edges,
                            int n_bins, int proj_blocks) {
    __shared__ int hist[MAX_BINS];      // per-bin counts
    __shared__ int segs[MAX_BINS];      // exclusive local starts
    __shared__ int tmp [MAX_BINS];      // scan ping-pong, then lofs
    __shared__ int gbase[MAX_BINS];     // claimed global bases
    __shared__ unsigned sorted[P1_EDGES];

    if ((int)blockIdx.x >= proj_blocks) {
        // ---- bin pass 1: block-local counting sort over its edge range ----
        const int bid = (int)blockIdx.x - proj_blocks;
        const int e0 = bid * P1_EDGES;
        const int e1 = min(e0 + P1_EDGES, n_edges);
        const int cnt = e1 - e0;

        for (int i = threadIdx.x; i < MAX_BINS; i += 256) hist[i] = 0;
        __syncthreads();
        for (int e = e0 + (int)threadIdx.x; e < e1; e += 256)
            atomicAdd(&hist[row[e] >> BIN_SHIFT], 1);
        __syncthreads();
        // inclusive scan (Hillis-Steele over MAX_BINS) into segs
        for (int i = threadIdx.x; i < MAX_BINS; i += 256) segs[i] = hist[i];
        __syncthreads();
        for (int s = 1; s < MAX_BINS; s <<= 1) {
            for (int i = threadIdx.x; i < MAX_BINS; i += 256)
                tmp[i] = (i >= s) ? segs[i - s] + segs[i] : segs[i];
            __syncthreads();
            for (int i = threadIdx.x; i < MAX_BINS; i += 256) segs[i] = tmp[i];
            __syncthreads();
        }
        // segs -> exclusive; claim global bases; init lofs (tmp)
        for (int i = threadIdx.x; i < MAX_BINS; i += 256) {
            const int hc = hist[i];
            const int ex = segs[i] - hc;
            tmp[i] = ex;                 // lofs
            segs[i] = ex;                // keep exclusive start for pass C
            gbase[i] = hc > 0 ? atomicAdd(&cursor[i * 16], hc) : 0;
        }
        __syncthreads();
        // pass B: scatter records into LDS-sorted order
        for (int e = e0 + (int)threadIdx.x; e < e1; e += 256) {
            const int r = row[e];
            const unsigned rec = (unsigned)r | ((unsigned)col[e] << 16);
            const int pos = atomicAdd(&tmp[r >> BIN_SHIFT], 1);
            sorted[pos] = rec;
        }
        __syncthreads();
        // pass C: segment-contiguous coalesced stores to scratch
        for (int i = threadIdx.x; i < cnt; i += 256) {
            const unsigned rec = sorted[i];
            const int bn = (int)(rec & 0xFFFFu) >> BIN_SHIFT;
            const int off = gbase[bn] + (i - segs[bn]);
            if (off < BIN_CAP) {
                scratch[(size_t)bn * BIN_CAP + off] = rec;
            } else {
                const int k = atomicAdd(ovfA_cnt, 1);
                if (k < ovfA_cap) ovfA_list[k] = rec;
            }
        }
        return;
    }

    // ---- projection (proven R5-R9 MFMA path) ----
    const int lane = (int)threadIdx.x & 63;
    const int wid  = (int)((blockIdx.x * 256 + threadIdx.x) >> 6);
    const int nwaves = proj_blocks * 4;
    const int m    = lane & 15;
    const int quad = lane >> 4;

    frag_ab Bf[4][4];
#pragma unroll
    for (int kk = 0; kk < 4; ++kk) {
#pragma unroll
        for (int nt = 0; nt < 4; ++nt) {
            const float* wp = W + (size_t)(nt * 16 + m) * D_IN + kk * 32 + quad * 8;
            const float4 w0 = *(const float4*)wp;
            const float4 w1 = *(const float4*)(wp + 4);
            frag_ab f;
            f[0] = f2bf(w0.x); f[1] = f2bf(w0.y); f[2] = f2bf(w0.z); f[3] = f2bf(w0.w);
            f[4] = f2bf(w1.x); f[5] = f2bf(w1.y); f[6] = f2bf(w1.z); f[7] = f2bf(w1.w);
            Bf[kk][nt] = f;
        }
    }
    float bb[4];
#pragma unroll
    for (int nt = 0; nt < 4; ++nt) bb[nt] = bvec[nt * 16 + m];

    const int ntiles = (n_nodes + 15) / 16;
    for (int tile = wid; tile < ntiles; tile += nwaves) {
        const int node_base = tile * 16;
        int arow = node_base + m;
        if (arow > n_nodes - 1) arow = n_nodes - 1;

        float4 xv[8];
        const float* xr = x + (size_t)arow * D_IN + quad * 8;
#pragma unroll
        for (int kk = 0; kk < 4; ++kk) {
            xv[2 * kk]     = *(const float4*)(xr + kk * 32);
            xv[2 * kk + 1] = *(const float4*)(xr + kk * 32 + 4);
        }

        frag_cd acc[4];
#pragma unroll
        for (int nt = 0; nt < 4; ++nt) {
            acc[nt][0] = bb[nt]; acc[nt][1] = bb[nt];
            acc[nt][2] = bb[nt]; acc[nt][3] = bb[nt];
        }
#pragma unroll
        for (int kk = 0; kk < 4; ++kk) {
            const float4 x0 = xv[2 * kk], x1 = xv[2 * kk + 1];
            frag_ab A;
            A[0] = f2bf(x0.x); A[1] = f2bf(x0.y); A[2] = f2bf(x0.z); A[3] = f2bf(x0.w);
            A[4] = f2bf(x1.x); A[5] = f2bf(x1.y); A[6] = f2bf(x1.z); A[7] = f2bf(x1.w);
#pragma unroll
            for (int nt = 0; nt < 4; ++nt)
                acc[nt] = __builtin_amdgcn_mfma_f32_16x16x32_bf16(A, Bf[kk][nt],
                                                                  acc[nt], 0, 0, 0);
        }
#pragma unroll
        for (int nt = 0; nt < 4; ++nt) {
#pragma unroll
            for (int r = 0; r < 4; ++r) {
                const int node = node_base + quad * 4 + r;
                if (node < n_nodes)
                    h[(size_t)node * D_OUT + nt * 16 + m] =
                        (unsigned short)f2bf(acc[nt][r]);
            }
        }
    }
}

// ---------------------------------------------------------------------------
// Fused sort+gather: one block per bin (128 nodes). Build an exact LDS
// counting sort of the bin's records by destination node (no CAP, any
// degree), then gather: lane = channel, indices via broadcast LDS reads,
// 8-wide unrolled independent 128B h-row loads, fused mean, coalesced
// 256B/wave stores. ovfA handled inline (zero work in practice).
// ---------------------------------------------------------------------------
__global__ __launch_bounds__(GT_THREADS)
void gatherf_kernel(const unsigned* __restrict__ scratch,
                    const int* __restrict__ cursor,
                    const unsigned short* __restrict__ h16,
                    const int* __restrict__ ovfA_cnt,
                    const unsigned* __restrict__ ovfA_list, int ovfA_cap,
                    float* __restrict__ out, int n_nodes) {
    __shared__ int ldeg[BIN_NODES];
    __shared__ int sstart[BIN_NODES];
    __shared__ int lofs[BIN_NODES];
    __shared__ int scan[BIN_NODES];
    __shared__ unsigned short sidx[BIN_CAP];   // sorted cols, 8 KB
    const int bin = (int)blockIdx.x;
    const int node0 = bin << BIN_SHIFT;
    const int nrows = min(BIN_NODES, n_nodes - node0);
    int cnt = cursor[bin * 16]; if (cnt > BIN_CAP) cnt = BIN_CAP;
    const unsigned* sbin = scratch + (size_t)bin * BIN_CAP;

    if (threadIdx.x < BIN_NODES) ldeg[threadIdx.x] = 0;
    __syncthreads();
    for (int i = threadIdx.x; i < cnt; i += GT_THREADS)
        atomicAdd(&ldeg[sbin[i] & (BIN_NODES - 1)], 1);
    __syncthreads();
    // inclusive scan of ldeg -> scan
    if (threadIdx.x < BIN_NODES) scan[threadIdx.x] = ldeg[threadIdx.x];
    __syncthreads();
    for (int s = 1; s < BIN_NODES; s <<= 1) {
        int v = 0;
        if (threadIdx.x < BIN_NODES)
            v = (threadIdx.x >= s) ? scan[threadIdx.x - s] + scan[threadIdx.x]
                                   : scan[threadIdx.x];
        __syncthreads();
        if (threadIdx.x < BIN_NODES) scan[threadIdx.x] = v;
        __syncthreads();
    }
    if (threadIdx.x < BIN_NODES) {
        const int ex = scan[threadIdx.x] - ldeg[threadIdx.x];
        sstart[threadIdx.x] = ex;
        lofs[threadIdx.x] = ex;
    }
    __syncthreads();
    for (int i = threadIdx.x; i < cnt; i += GT_THREADS) {
        const unsigned rec = sbin[i];
        const int pos = atomicAdd(&lofs[rec & (BIN_NODES - 1)], 1);
        sidx[pos] = (unsigned short)(rec >> 16);
    }
    __syncthreads();

    // ---- gather: wave w handles nodes w*16 .. w*16+15 ----
    const int wv = (int)threadIdx.x >> 6;
    const int lane = (int)threadIdx.x & 63;
    int cA = *ovfA_cnt; if (cA > ovfA_cap) cA = ovfA_cap;

    for (int rl = wv * 16; rl < min(wv * 16 + 16, nrows); ++rl) {
        const int s0 = sstart[rl];
        int d = ldeg[rl];
        float acc = 0.f;
        int k = 0;
        for (; k + 8 <= d; k += 8) {
            unsigned short idx[8];
#pragma unroll
            for (int j = 0; j < 8; ++j) idx[j] = sidx[s0 + k + j];  // broadcast
#pragma unroll
            for (int j = 0; j < 8; ++j)
                acc += bf1(h16[(size_t)idx[j] * D_OUT + lane]);
        }
        for (; k < d; ++k)
            acc += bf1(h16[(size_t)sidx[s0 + k] * D_OUT + lane]);

        if (cA > 0) {   // rare exact path: pass-1 overflow records
            const int node = node0 + rl;
            for (int t = 0; t < cA; ++t) {
                const unsigned rec = ovfA_list[t];
                if ((int)(rec & 0xFFFFu) == node) {
                    acc += bf1(h16[(size_t)(rec >> 16) * D_OUT + lane]);
                    ++d;
                }
            }
        }
        out[(size_t)(node0 + rl) * D_OUT + lane] =
            acc * (1.0f / fmaxf((float)d, 1.0f));
    }
}

// ---------------------------------------------------------------------------
// Fallback path (ws too small or n_nodes > 65536): fp32 h + atomic scatter.
// ---------------------------------------------------------------------------
__global__ void proj_only_kernel(const float* __restrict__ x,
                                 const float* __restrict__ W,
                                 const float* __restrict__ bvec,
                                 float* __restrict__ h, int n_nodes) {
    const int lane = (int)threadIdx.x & 63;
    const int wave = (int)((blockIdx.x * blockDim.x + threadIdx.x) >> 6);
    const int nwaves = (int)((gridDim.x * blockDim.x) >> 6);
    const float bias = bvec[lane];
    for (int node = wave; node < n_nodes; node += nwaves) {
        const float* xr = &x[(size_t)node * D_IN];
        float acc = bias;
#pragma unroll
        for (int k = 0; k < D_IN; ++k) acc += xr[k] * W[lane * D_IN + k];
        h[(size_t)node * D_OUT + lane] = acc;
    }
}

__global__ void scatter_kernel(const float* __restrict__ h,
                               const int* __restrict__ row,
                               const int* __restrict__ col,
                               float* __restrict__ out,
                               int* __restrict__ deg,
                               long long n_tasks) {
    long long t = (long long)blockIdx.x * blockDim.x + threadIdx.x;
    const long long stride = (long long)gridDim.x * blockDim.x;
    for (; t < n_tasks; t += stride) {
        const int e = (int)(t >> 6);
        const int c = (int)(t & 63);
        atomicAdd(&out[(size_t)row[e] * D_OUT + c], h[(size_t)col[e] * D_OUT + c]);
        if (c == 0) atomicAdd(&deg[row[e]], 1);
    }
}

__global__ void div_kernel(float* __restrict__ out,
                           const int* __restrict__ deg, int n_total) {
    int t = blockIdx.x * blockDim.x + threadIdx.x;
    if (t < n_total) {
        out[t] *= 1.0f / fmaxf((float)deg[t >> 6], 1.0f);
    }
}

extern "C" void kernel_launch(void* const* d_in, const int* in_sizes, int n_in,
                              void* d_out, int out_size, void* d_ws, size_t ws_size,
                              hipStream_t stream) {
    const float* x   = (const float*)d_in[0];
    const float* W   = (const float*)d_in[1];
    const float* b   = (const float*)d_in[2];
    const int*   row = (const int*)d_in[3];
    const int*   col = (const int*)d_in[4];
    float* out = (float*)d_out;

    const int n_nodes = in_sizes[0] / D_IN;
    const int n_edges = in_sizes[3];
    const int n_bins  = (n_nodes + BIN_NODES - 1) >> BIN_SHIFT;

    // Workspace: h(bf16) | ovf_cnts(256B) | cursor(padded) | ovfA | scratch
    char* p = (char*)d_ws;
    unsigned short* h = (unsigned short*)p;
    p += (size_t)n_nodes * D_OUT * sizeof(unsigned short);
    int* ovf_cnts = (int*)p;       p += 256;
    int* cursor = (int*)p;         p += (size_t)MAX_BINS * 16 * sizeof(int);
    unsigned* ovfA_list = (unsigned*)p;  p += (size_t)n_edges * sizeof(unsigned);
    unsigned* scratch = (unsigned*)p;
    p += (size_t)n_bins * BIN_CAP * sizeof(unsigned);
    const size_t needed = (size_t)(p - (char*)d_ws);

    if (ws_size >= needed && n_nodes <= MAX_USHORT_NODES && n_bins <= MAX_BINS) {
        // one small memset: ovf counters + padded cursor (~33 KB)
        hipMemsetAsync(ovf_cnts, 0, 256 + (size_t)MAX_BINS * 16 * sizeof(int),
                       stream);

        // 1) fused projection + pass-1 sorter
        const int ntiles = (n_nodes + 15) / 16;
        const int proj_blocks = (ntiles + 3) / 4;                 // 1 tile/wave
        const int p1_blocks = (n_edges + P1_EDGES - 1) / P1_EDGES;
        prep_kernel<<<proj_blocks + p1_blocks, 256, 0, stream>>>(
            x, W, b, h, row, col, scratch, cursor, &ovf_cnts[0], ovfA_list,
            n_edges, n_nodes, n_edges, n_bins, proj_blocks);

        // 2) fused per-bin sort + gather + mean
        gatherf_kernel<<<n_bins, GT_THREADS, 0, stream>>>(
            scratch, cursor, h, &ovf_cnts[0], ovfA_list, n_edges,
            out, n_nodes);
    } else {
        // fallback: fp32 h + atomic scatter
        float* hf = (float*)d_ws;
        int* degf = (int*)((char*)d_ws + (size_t)n_nodes * D_OUT * sizeof(float));
        hipMemsetAsync(out, 0, (size_t)out_size * sizeof(float), stream);
        hipMemsetAsync(degf, 0, (size_t)n_nodes * sizeof(int), stream);
        proj_only_kernel<<<1024, 256, 0, stream>>>(x, W, b, hf, n_nodes);
        const long long n_tasks = (long long)n_edges * D_OUT;
        scatter_kernel<<<16384, 256, 0, stream>>>(hf, row, col, out, degf, n_tasks);
        const int n_total = n_nodes * D_OUT;
        div_kernel<<<(n_total + 255) / 256, 256, 0, stream>>>(out, degf, n_total);
    }
}

// Round 11
// 135.323 us; speedup vs baseline: 1.1092x; 1.1092x over previous
//
#include <hip/hip_runtime.h>
#include <hip/hip_bf16.h>

#define D_IN   128
#define D_OUT  64
#define CAP    32          // per-node bucket capacity; overflow exact via ovfB
#define MAX_USHORT_NODES 65536
#define BIN_SHIFT 8        // 256 node ids per bin
#define MAX_BINS  256
#define BIN_CAP   8192     // scratch slots per bin (expected ~4096)
#define P1_EDGES  2048     // edges per pass-1 sorter block
#define P2_THREADS 512

using frag_ab = __attribute__((ext_vector_type(8))) short;  // 8 bf16
using frag_cd = __attribute__((ext_vector_type(4))) float;  // 4 fp32

static __device__ __forceinline__ short f2bf(float f) {
    union { float f; unsigned u; } v; v.f = f;
    unsigned r = v.u + 0x7FFFu + ((v.u >> 16) & 1u);   // RNE truncate to bf16
    return (short)(r >> 16);
}
static __device__ __forceinline__ float bf1(unsigned short s) {
    union { unsigned u; float f; } v; v.u = ((unsigned)s) << 16; return v.f;
}

// ---------------------------------------------------------------------------
// Fused prep: blocks [0, proj_blocks) = MFMA projection (wave = 16-node
// tile). Blocks [proj_blocks, ...) = bin pass 1 as a block-local LDS
// counting sort over a 2048-edge slice: histogram -> prefix scan -> LDS-
// sorted records -> claim contiguous per-bin global ranges -> SEGMENT-
// CONTIGUOUS coalesced stores (kills per-edge scattered-4B line amp).
// Record format: r | c<<16. Static LDS: 12 KB (proj occupancy unharmed).
// ---------------------------------------------------------------------------
__global__ void prep_kernel(const float* __restrict__ x,
                            const float* __restrict__ W,
                            const float* __restrict__ bvec,
                            unsigned short* __restrict__ h,
                            const int* __restrict__ row,
                            const int* __restrict__ col,
                            unsigned* __restrict__ scratch,
                            int* __restrict__ cursor,
                            int* __restrict__ ovfA_cnt,
                            unsigned* __restrict__ ovfA_list,
                            int ovfA_cap, int n_nodes, int n_edges,
                            int proj_blocks) {
    __shared__ int hist[MAX_BINS];       // counts, then exclusive starts
    __shared__ int segs[MAX_BINS];       // scan workspace (inclusive)
    __shared__ int lofs[MAX_BINS];       // running fill cursors
    __shared__ int gbase[MAX_BINS];      // claimed global bases
    __shared__ unsigned sorted[P1_EDGES];   // 8 KB

    if ((int)blockIdx.x >= proj_blocks) {
        const int bid = (int)blockIdx.x - proj_blocks;
        const int e0 = bid * P1_EDGES;
        const int e1 = min(e0 + P1_EDGES, n_edges);
        const int cnt = e1 - e0;
        const int i = (int)threadIdx.x;   // 256 threads == MAX_BINS

        hist[i] = 0;
        __syncthreads();
        for (int e = e0 + i; e < e1; e += 256)
            atomicAdd(&hist[row[e] >> BIN_SHIFT], 1);
        __syncthreads();
        segs[i] = hist[i];
        __syncthreads();
        for (int s = 1; s < MAX_BINS; s <<= 1) {
            int v = segs[i];
            if (i >= s) v += segs[i - s];
            __syncthreads();
            segs[i] = v;
            __syncthreads();
        }
        {
            const int hc = hist[i];
            const int ex = segs[i] - hc;    // exclusive local start
            lofs[i] = ex;
            hist[i] = ex;                   // keep for pass C
            gbase[i] = hc > 0 ? atomicAdd(&cursor[i * 16], hc) : 0;
        }
        __syncthreads();
        // pass B: scatter into LDS-sorted (bin-grouped) order
        for (int e = e0 + i; e < e1; e += 256) {
            const int r = row[e];
            const unsigned rec = (unsigned)r | ((unsigned)col[e] << 16);
            const int pos = atomicAdd(&lofs[r >> BIN_SHIFT], 1);
            sorted[pos] = rec;
        }
        __syncthreads();
        // pass C: segment-contiguous coalesced stores to scratch
        for (int k = i; k < cnt; k += 256) {
            const unsigned rec = sorted[k];
            const int bn = (int)(rec & 0xFFFFu) >> BIN_SHIFT;
            const int off = gbase[bn] + (k - hist[bn]);
            if (off < BIN_CAP) {
                scratch[(size_t)bn * BIN_CAP + off] = rec;
            } else {
                const int t = atomicAdd(ovfA_cnt, 1);
                if (t < ovfA_cap) ovfA_list[t] = rec;
            }
        }
        return;
    }

    // ---- projection (proven R5-R9 MFMA path) ----
    const int lane = (int)threadIdx.x & 63;
    const int wid  = (int)((blockIdx.x * 256 + threadIdx.x) >> 6);
    const int nwaves = proj_blocks * 4;
    const int m    = lane & 15;
    const int quad = lane >> 4;

    frag_ab Bf[4][4];
#pragma unroll
    for (int kk = 0; kk < 4; ++kk) {
#pragma unroll
        for (int nt = 0; nt < 4; ++nt) {
            const float* wp = W + (size_t)(nt * 16 + m) * D_IN + kk * 32 + quad * 8;
            const float4 w0 = *(const float4*)wp;
            const float4 w1 = *(const float4*)(wp + 4);
            frag_ab f;
            f[0] = f2bf(w0.x); f[1] = f2bf(w0.y); f[2] = f2bf(w0.z); f[3] = f2bf(w0.w);
            f[4] = f2bf(w1.x); f[5] = f2bf(w1.y); f[6] = f2bf(w1.z); f[7] = f2bf(w1.w);
            Bf[kk][nt] = f;
        }
    }
    float bb[4];
#pragma unroll
    for (int nt = 0; nt < 4; ++nt) bb[nt] = bvec[nt * 16 + m];

    const int ntiles = (n_nodes + 15) / 16;
    for (int tile = wid; tile < ntiles; tile += nwaves) {
        const int node_base = tile * 16;
        int arow = node_base + m;
        if (arow > n_nodes - 1) arow = n_nodes - 1;

        float4 xv[8];
        const float* xr = x + (size_t)arow * D_IN + quad * 8;
#pragma unroll
        for (int kk = 0; kk < 4; ++kk) {
            xv[2 * kk]     = *(const float4*)(xr + kk * 32);
            xv[2 * kk + 1] = *(const float4*)(xr + kk * 32 + 4);
        }

        frag_cd acc[4];
#pragma unroll
        for (int nt = 0; nt < 4; ++nt) {
            acc[nt][0] = bb[nt]; acc[nt][1] = bb[nt];
            acc[nt][2] = bb[nt]; acc[nt][3] = bb[nt];
        }
#pragma unroll
        for (int kk = 0; kk < 4; ++kk) {
            const float4 x0 = xv[2 * kk], x1 = xv[2 * kk + 1];
            frag_ab A;
            A[0] = f2bf(x0.x); A[1] = f2bf(x0.y); A[2] = f2bf(x0.z); A[3] = f2bf(x0.w);
            A[4] = f2bf(x1.x); A[5] = f2bf(x1.y); A[6] = f2bf(x1.z); A[7] = f2bf(x1.w);
#pragma unroll
            for (int nt = 0; nt < 4; ++nt)
                acc[nt] = __builtin_amdgcn_mfma_f32_16x16x32_bf16(A, Bf[kk][nt],
                                                                  acc[nt], 0, 0, 0);
        }
#pragma unroll
        for (int nt = 0; nt < 4; ++nt) {
#pragma unroll
            for (int r = 0; r < 4; ++r) {
                const int node = node_base + quad * 4 + r;
                if (node < n_nodes)
                    h[(size_t)node * D_OUT + nt * 16 + m] =
                        (unsigned short)f2bf(acc[nt][r]);
            }
        }
    }
}

// ---------------------------------------------------------------------------
// Pass 2 (+fused A-overflow degfix): one block per bin. Exact deg + bucket
// rows in LDS, then atomicAdd deg and coalesced uint4 bucket stores.
// Record format: r | c<<16 (rl = r & 255).
// ---------------------------------------------------------------------------
__global__ __launch_bounds__(P2_THREADS)
void binpass2_kernel(const unsigned* __restrict__ scratch,
                     const int* __restrict__ cursor,
                     int* __restrict__ deg, unsigned short* __restrict__ bucket,
                     int* __restrict__ ovfB_cnt, unsigned* __restrict__ ovfB_list,
                     int ovfB_cap,
                     const int* __restrict__ ovfA_cnt,
                     const unsigned* __restrict__ ovfA_list, int ovfA_cap,
                     int n_nodes) {
    __shared__ int ldeg[256];
    __shared__ unsigned short lbuck[256 * CAP];   // 16 KB
    const int bin = (int)blockIdx.x;
    const int node0 = bin << BIN_SHIFT;
    const int nrows = min(256, n_nodes - node0);
    int cnt = cursor[bin * 16]; if (cnt > BIN_CAP) cnt = BIN_CAP;

    if (bin == 0) {
        int cA = *ovfA_cnt; if (cA > ovfA_cap) cA = ovfA_cap;
        for (int k = threadIdx.x; k < cA; k += P2_THREADS)
            atomicAdd(&deg[ovfA_list[k] & 0xFFFFu], 1);
    }

    for (int i = threadIdx.x; i < 256; i += P2_THREADS) ldeg[i] = 0;
    __syncthreads();
    for (int i = threadIdx.x; i < cnt; i += P2_THREADS) {
        const unsigned rec = scratch[(size_t)bin * BIN_CAP + i];
        const int rl = rec & 255;
        const int c  = (int)(rec >> 16);
        const int s = atomicAdd(&ldeg[rl], 1);
        if (s < CAP) {
            lbuck[(rl << 5) + s] = (unsigned short)c;
        } else {
            const int k = atomicAdd(ovfB_cnt, 1);
            if (k < ovfB_cap)
                ovfB_list[k] = (unsigned)(node0 + rl) | ((unsigned)c << 16);
        }
    }
    __syncthreads();
    for (int i = threadIdx.x; i < nrows; i += P2_THREADS)
        atomicAdd(&deg[node0 + i], ldeg[i]);
    uint4* dst = (uint4*)(bucket + (size_t)node0 * CAP);
    const uint4* src = (const uint4*)lbuck;
    const int nu4 = nrows * (CAP / 8);
    for (int i = threadIdx.x; i < nu4; i += P2_THREADS) dst[i] = src[i];
}

// ---------------------------------------------------------------------------
// Gather3 (unchanged from R9): one wave per node, lane = channel, scalar
// deg/bucket loads, 16/32 fully-unrolled independent 128B h-row loads,
// fused mean, inline overflow scan (zero work in practice).
// ---------------------------------------------------------------------------
__global__ __launch_bounds__(256)
void gather3_kernel(const unsigned short* __restrict__ h16,
                    const int* __restrict__ deg,
                    const unsigned short* __restrict__ bucket,
                    const int* __restrict__ ovf_cnts,   // [0]=A,[1]=B
                    const unsigned* __restrict__ ovfA_list,
                    const unsigned* __restrict__ ovfB_list,
                    int ovf_cap,
                    float* __restrict__ out, int n_nodes) {
    const int lane = (int)threadIdx.x & 63;
    const int wv = (int)((blockIdx.x * blockDim.x + threadIdx.x) >> 6);
    if (wv >= n_nodes) return;
    const int node = __builtin_amdgcn_readfirstlane(wv);

    const int d = deg[node];                       // uniform -> scalar load
    const int dc = d < CAP ? d : CAP;
    const unsigned* brow = (const unsigned*)(bucket + (size_t)node * CAP);
    unsigned rec[CAP / 2];
#pragma unroll
    for (int i = 0; i < CAP / 2; ++i) rec[i] = brow[i];   // uniform 64B row

    float acc = 0.f;
#pragma unroll
    for (int k = 0; k < 16; ++k) {
        const unsigned idx = (k & 1) ? (rec[k >> 1] >> 16)
                                     : (rec[k >> 1] & 0xFFFFu);
        const unsigned use = (k < dc) ? idx : 0u;          // clamp to hot row 0
        const float v = bf1(h16[(size_t)use * D_OUT + lane]);
        acc += (k < dc) ? v : 0.f;
    }
    if (dc > 16) {
#pragma unroll
        for (int k = 16; k < 32; ++k) {
            const unsigned idx = (k & 1) ? (rec[k >> 1] >> 16)
                                         : (rec[k >> 1] & 0xFFFFu);
            const unsigned use = (k < dc) ? idx : 0u;
            const float v = bf1(h16[(size_t)use * D_OUT + lane]);
            acc += (k < dc) ? v : 0.f;
        }
    }

    int cA = ovf_cnts[0]; if (cA > ovf_cap) cA = ovf_cap;
    int cB = ovf_cnts[1]; if (cB > ovf_cap) cB = ovf_cap;
    if (cA + cB > 0) {
        for (int k = 0; k < cA; ++k) {
            const unsigned r2 = ovfA_list[k];
            if ((int)(r2 & 0xFFFFu) == node)
                acc += bf1(h16[(size_t)(r2 >> 16) * D_OUT + lane]);
        }
        for (int k = 0; k < cB; ++k) {
            const unsigned r2 = ovfB_list[k];
            if ((int)(r2 & 0xFFFFu) == node)
                acc += bf1(h16[(size_t)(r2 >> 16) * D_OUT + lane]);
        }
    }

    out[(size_t)node * D_OUT + lane] = acc * (1.0f / fmaxf((float)d, 1.0f));
}

// ---------------------------------------------------------------------------
// Fallback path (ws too small or n_nodes > 65536): fp32 h + atomic scatter.
// ---------------------------------------------------------------------------
__global__ void proj_only_kernel(const float* __restrict__ x,
                                 const float* __restrict__ W,
                                 const float* __restrict__ bvec,
                                 float* __restrict__ h, int n_nodes) {
    const int lane = (int)threadIdx.x & 63;
    const int wave = (int)((blockIdx.x * blockDim.x + threadIdx.x) >> 6);
    const int nwaves = (int)((gridDim.x * blockDim.x) >> 6);
    const float bias = bvec[lane];
    for (int node = wave; node < n_nodes; node += nwaves) {
        const float* xr = &x[(size_t)node * D_IN];
        float acc = bias;
#pragma unroll
        for (int k = 0; k < D_IN; ++k) acc += xr[k] * W[lane * D_IN + k];
        h[(size_t)node * D_OUT + lane] = acc;
    }
}

__global__ void scatter_kernel(const float* __restrict__ h,
                               const int* __restrict__ row,
                               const int* __restrict__ col,
                               float* __restrict__ out,
                               int* __restrict__ deg,
                               long long n_tasks) {
    long long t = (long long)blockIdx.x * blockDim.x + threadIdx.x;
    const long long stride = (long long)gridDim.x * blockDim.x;
    for (; t < n_tasks; t += stride) {
        const int e = (int)(t >> 6);
        const int c = (int)(t & 63);
        atomicAdd(&out[(size_t)row[e] * D_OUT + c], h[(size_t)col[e] * D_OUT + c]);
        if (c == 0) atomicAdd(&deg[row[e]], 1);
    }
}

__global__ void div_kernel(float* __restrict__ out,
                           const int* __restrict__ deg, int n_total) {
    int t = blockIdx.x * blockDim.x + threadIdx.x;
    if (t < n_total) {
        out[t] *= 1.0f / fmaxf((float)deg[t >> 6], 1.0f);
    }
}

extern "C" void kernel_launch(void* const* d_in, const int* in_sizes, int n_in,
                              void* d_out, int out_size, void* d_ws, size_t ws_size,
                              hipStream_t stream) {
    const float* x   = (const float*)d_in[0];
    const float* W   = (const float*)d_in[1];
    const float* b   = (const float*)d_in[2];
    const int*   row = (const int*)d_in[3];
    const int*   col = (const int*)d_in[4];
    float* out = (float*)d_out;

    const int n_nodes = in_sizes[0] / D_IN;
    const int n_edges = in_sizes[3];
    const int n_bins  = (n_nodes + 255) >> BIN_SHIFT;

    // Workspace: h(bf16) | deg | ovf_cnts(256B) | cursor(padded) | ovfA | ovfB
    //            | bucket(ushort) | scratch    (deg..cursor zeroed together)
    char* p = (char*)d_ws;
    unsigned short* h = (unsigned short*)p;
    p += (size_t)n_nodes * D_OUT * sizeof(unsigned short);
    int* deg = (int*)p;            p += (size_t)n_nodes * sizeof(int);
    int* ovf_cnts = (int*)p;       p += 256;                       // [0]=A, [1]=B
    int* cursor = (int*)p;         p += (size_t)MAX_BINS * 16 * sizeof(int);
    unsigned* ovfA_list = (unsigned*)p;  p += (size_t)n_edges * sizeof(unsigned);
    unsigned* ovfB_list = (unsigned*)p;  p += (size_t)n_edges * sizeof(unsigned);
    unsigned short* bucket = (unsigned short*)p;
    p += (size_t)n_nodes * CAP * sizeof(unsigned short);
    unsigned* scratch = (unsigned*)p;
    p += (size_t)n_bins * BIN_CAP * sizeof(unsigned);
    const size_t needed = (size_t)(p - (char*)d_ws);

    if (ws_size >= needed && n_nodes <= MAX_USHORT_NODES) {
        // one memset: deg + ovf counters + cursor (contiguous)
        hipMemsetAsync(deg, 0,
                       (size_t)n_nodes * sizeof(int) + 256 +
                       (size_t)MAX_BINS * 16 * sizeof(int), stream);

        // 1) fused projection + pass-1 counting sorter
        const int ntiles = (n_nodes + 15) / 16;
        const int proj_blocks = (ntiles + 3) / 4;   // 1 tile per wave
        const int p1_blocks = (n_edges + P1_EDGES - 1) / P1_EDGES;
        prep_kernel<<<proj_blocks + p1_blocks, 256, 0, stream>>>(
            x, W, b, h, row, col, scratch, cursor, &ovf_cnts[0], ovfA_list,
            n_edges, n_nodes, n_edges, proj_blocks);

        // 2) bin pass 2 (+fused degfix)
        binpass2_kernel<<<n_bins, P2_THREADS, 0, stream>>>(
            scratch, cursor, deg, bucket, &ovf_cnts[1], ovfB_list, n_edges,
            &ovf_cnts[0], ovfA_list, n_edges, n_nodes);

        // 3) gather3 (scalar-indexed, fused mean + overflow)
        const int grid = (n_nodes + 3) / 4;         // 1 wave per node
        gather3_kernel<<<grid, 256, 0, stream>>>(
            h, deg, bucket, ovf_cnts, ovfA_list, ovfB_list, n_edges,
            out, n_nodes);
    } else {
        // fallback: fp32 h + atomic scatter
        float* hf = (float*)d_ws;
        int* degf = (int*)((char*)d_ws + (size_t)n_nodes * D_OUT * sizeof(float));
        hipMemsetAsync(out, 0, (size_t)out_size * sizeof(float), stream);
        hipMemsetAsync(degf, 0, (size_t)n_nodes * sizeof(int), stream);
        proj_only_kernel<<<1024, 256, 0, stream>>>(x, W, b, hf, n_nodes);
        const long long n_tasks = (long long)n_edges * D_OUT;
        scatter_kernel<<<16384, 256, 0, stream>>>(hf, row, col, out, degf, n_tasks);
        const int n_total = n_nodes * D_OUT;
        div_kernel<<<(n_total + 255) / 256, 256, 0, stream>>>(out, degf, n_total);
    }
}